// Round 1
// baseline (1165.744 us; speedup 1.0000x reference)
//
#include <hip/hip_runtime.h>
#include <hip/hip_bf16.h>

// Problem sizes
#define BB 8
#define CC 192
#define C3 576
#define NH 4
#define CH 48
#define HH 128
#define WW 128
#define HW 16384
#define FF 6144

constexpr int NFC = 12;                  // f-chunks for QK^T partials (4 ch each)
constexpr size_t SPM = 32ull * 128 * 128;  // elems per partial-S chunk

// workspace layout (bytes)
constexpr size_t SZ_RAW = (size_t)BB * C3 * HW * 2;   // bf16 qkv (pre-dw)
constexpr size_t OFF_RAW = 0;                          // reused as fp32 attn_out later
constexpr size_t OFF_DW  = OFF_RAW + SZ_RAW;           // bf16 qkv (post-dw)
constexpr size_t OFF_SP  = OFF_DW + SZ_RAW;            // fp32 partial S [12][32][128][128]
constexpr size_t OFF_RQ  = OFF_SP + (size_t)NFC * SPM * 4;
constexpr size_t OFF_RK  = OFF_RQ + 32 * 128 * 4;
constexpr size_t OFF_AT  = OFF_RK + 32 * 128 * 4;      // fp32 attn [32][128][128]

__device__ __forceinline__ void store_out(__hip_bfloat16* p, float v) { *p = __float2bfloat16(v); }
__device__ __forceinline__ void store_out(float* p, float v) { *p = v; }

// out[b,o,p] = sum_c wgt[o*192+c] * x[b,c,p]   (tiled 64x64, K-chunks of 32)
template <int M, typename OutT>
__global__ __launch_bounds__(256) void k_conv1x1(const float* __restrict__ x,
                                                 const float* __restrict__ wgt,
                                                 OutT* __restrict__ out) {
  const int pBase = blockIdx.x * 64;
  const int oBase = blockIdx.y * 64;
  const int b = blockIdx.z;
  const float* xb = x + (size_t)b * CC * HW;
  OutT* ob = out + (size_t)b * M * HW;

  __shared__ float Wt[64][33];   // [o][k]
  __shared__ float Xt[32][64];   // [k][p]

  const int tid = threadIdx.x;
  const int tx = tid & 15;       // p group (4)
  const int ty = tid >> 4;       // o group (4)
  float acc[4][4] = {};

  for (int k0 = 0; k0 < CC; k0 += 32) {
    {
      const int o = tid >> 2;
      const int k = (tid & 3) * 8;
      const float* s = wgt + (size_t)(oBase + o) * CC + k0 + k;
#pragma unroll
      for (int j = 0; j < 8; ++j) Wt[o][k + j] = s[j];
    }
    {
      const int k = tid >> 3;
      const int p = (tid & 7) * 8;
      const float* s = xb + (size_t)(k0 + k) * HW + pBase + p;
#pragma unroll
      for (int j = 0; j < 8; ++j) Xt[k][p + j] = s[j];
    }
    __syncthreads();
#pragma unroll
    for (int k = 0; k < 32; ++k) {
      float a[4], bv[4];
#pragma unroll
      for (int i = 0; i < 4; ++i) a[i] = Wt[ty * 4 + i][k];
#pragma unroll
      for (int j = 0; j < 4; ++j) bv[j] = Xt[k][tx * 4 + j];
#pragma unroll
      for (int i = 0; i < 4; ++i)
#pragma unroll
        for (int j = 0; j < 4; ++j) acc[i][j] += a[i] * bv[j];
    }
    __syncthreads();
  }
#pragma unroll
  for (int i = 0; i < 4; ++i) {
    OutT* dst = ob + (size_t)(oBase + ty * 4 + i) * HW + pBase + tx * 4;
#pragma unroll
    for (int j = 0; j < 4; ++j) store_out(dst + j, acc[i][j]);
  }
}

// depthwise 3x3, pad 1 (cross-correlation, matches lax.conv)
__global__ __launch_bounds__(256) void k_dwconv(const __hip_bfloat16* __restrict__ in,
                                                const float* __restrict__ wdw,
                                                __hip_bfloat16* __restrict__ out) {
  const int b = blockIdx.z;
  const int c = blockIdx.y;
  const int h = blockIdx.x * 2 + (threadIdx.x >> 7);
  const int w = threadIdx.x & 127;
  const __hip_bfloat16* src = in + ((size_t)b * C3 + c) * HW;
  const float* wp = wdw + c * 9;
  float acc = 0.f;
#pragma unroll
  for (int dh = -1; dh <= 1; ++dh) {
    const int hh = h + dh;
    if (hh < 0 || hh >= HH) continue;
#pragma unroll
    for (int dw = -1; dw <= 1; ++dw) {
      const int ww2 = w + dw;
      if (ww2 < 0 || ww2 >= WW) continue;
      acc += __bfloat162float(src[hh * WW + ww2]) * wp[(dh + 1) * 3 + (dw + 1)];
    }
  }
  out[((size_t)b * C3 + c) * HW + h * WW + w] = __float2bfloat16(acc);
}

// reciprocal L2 norms of q,k rows (over f = ch*128+w, 6144 elems)
__global__ __launch_bounds__(256) void k_norms(const __hip_bfloat16* __restrict__ dw,
                                               float* __restrict__ rq, float* __restrict__ rk) {
  const int i = blockIdx.x;
  const int hd = blockIdx.y;
  const int b = blockIdx.z & 7;
  const int which = blockIdx.z >> 3;   // 0=q, 1=k
  const __hip_bfloat16* base = dw + ((size_t)b * C3 + which * CC + hd * CH) * HW + i * WW;
  float s = 0.f;
  for (int t = threadIdx.x; t < FF; t += 256) {
    const int ch = t >> 7, w = t & 127;
    const float v = __bfloat162float(base[(size_t)ch * HW + w]);
    s += v * v;
  }
  __shared__ float red[4];
  const int lane = threadIdx.x & 63, wv = threadIdx.x >> 6;
#pragma unroll
  for (int off = 32; off > 0; off >>= 1) s += __shfl_down(s, off);
  if (lane == 0) red[wv] = s;
  __syncthreads();
  if (threadIdx.x == 0) {
    const float n = sqrtf(red[0] + red[1] + red[2] + red[3]);
    float* dst = which ? rk : rq;
    dst[(b * NH + hd) * HH + i] = 1.f / fmaxf(n, 1e-12f);
  }
}

// partial S over a 512-feature chunk: sp[fc][bh][i][j] = sum_f q[i,f]*k[j,f]
__global__ __launch_bounds__(256) void k_qk(const __hip_bfloat16* __restrict__ dw,
                                            float* __restrict__ sp) {
  const int fc = blockIdx.x;          // 0..11 (4 channels each)
  const int i0 = blockIdx.y * 64;     // 0, 64
  const int bh = blockIdx.z;          // b*4+hd
  const int b = bh >> 2, hd = bh & 3;
  const __hip_bfloat16* qb = dw + ((size_t)b * C3 + hd * CH + fc * 4) * HW;
  const __hip_bfloat16* kb = qb + (size_t)CC * HW;

  __shared__ float Qt[16][64];    // [kf][i]
  __shared__ float Kt[16][128];   // [kf][j]

  const int tid = threadIdx.x;
  const int tx = tid & 15;   // j group (8)
  const int ty = tid >> 4;   // i group (4)
  float acc[4][8] = {};

  for (int kc = 0; kc < 32; ++kc) {
    const int chl = kc >> 3;          // 0..3
    const int w0 = (kc & 7) * 16;     // 0..112
    {
      const int i = tid >> 2;
      const int kf0 = (tid & 3) * 4;
      const __hip_bfloat16* s = qb + (size_t)chl * HW + (i0 + i) * WW + w0 + kf0;
#pragma unroll
      for (int j = 0; j < 4; ++j) Qt[kf0 + j][i] = __bfloat162float(s[j]);
    }
    {
      const int jj = tid >> 1;
      const int kf0 = (tid & 1) * 8;
      const __hip_bfloat16* s = kb + (size_t)chl * HW + jj * WW + w0 + kf0;
#pragma unroll
      for (int j = 0; j < 8; ++j) Kt[kf0 + j][jj] = __bfloat162float(s[j]);
    }
    __syncthreads();
#pragma unroll
    for (int kf = 0; kf < 16; ++kf) {
      float a[4], bv[8];
#pragma unroll
      for (int ii = 0; ii < 4; ++ii) a[ii] = Qt[kf][ty * 4 + ii];
#pragma unroll
      for (int jj = 0; jj < 8; ++jj) bv[jj] = Kt[kf][tx * 8 + jj];
#pragma unroll
      for (int ii = 0; ii < 4; ++ii)
#pragma unroll
        for (int jj = 0; jj < 8; ++jj) acc[ii][jj] += a[ii] * bv[jj];
    }
    __syncthreads();
  }
  float* o = sp + (size_t)fc * SPM + ((size_t)bh * HH + i0) * HH;
#pragma unroll
  for (int ii = 0; ii < 4; ++ii)
#pragma unroll
    for (int jj = 0; jj < 8; ++jj)
      o[(ty * 4 + ii) * HH + tx * 8 + jj] = acc[ii][jj];
}

// reduce partials, scale by rq*rk*temp, softmax over j
__global__ __launch_bounds__(64) void k_softmax(const float* __restrict__ sp,
                                                const float* __restrict__ rq,
                                                const float* __restrict__ rk,
                                                const float* __restrict__ temp,
                                                float* __restrict__ attn) {
  const int i = blockIdx.x;
  const int bh = blockIdx.y;
  const int hd = bh & 3;
  const int lane = threadIdx.x;
  const size_t rowoff = ((size_t)bh * HH + i) * HH;
  float s0 = 0.f, s1 = 0.f;
#pragma unroll
  for (int fc = 0; fc < NFC; ++fc) {
    s0 += sp[fc * SPM + rowoff + lane];
    s1 += sp[fc * SPM + rowoff + lane + 64];
  }
  const float scale = rq[bh * HH + i] * temp[hd];
  s0 *= scale * rk[bh * HH + lane];
  s1 *= scale * rk[bh * HH + lane + 64];
  float m = fmaxf(s0, s1);
#pragma unroll
  for (int off = 32; off > 0; off >>= 1) m = fmaxf(m, __shfl_xor(m, off));
  const float e0 = expf(s0 - m), e1 = expf(s1 - m);
  float ssum = e0 + e1;
#pragma unroll
  for (int off = 32; off > 0; off >>= 1) ssum += __shfl_xor(ssum, off);
  const float inv = 1.f / ssum;
  attn[rowoff + lane] = e0 * inv;
  attn[rowoff + lane + 64] = e1 * inv;
}

// out[b, hd*48+ch, i, w] = sum_j attn[bh,i,j] * v[b, 384+hd*48+ch, j, w]
__global__ __launch_bounds__(256) void k_pv(const float* __restrict__ attn,
                                            const __hip_bfloat16* __restrict__ dw,
                                            float* __restrict__ outc) {
  const int bh = blockIdx.z;
  const int b = bh >> 2, hd = bh & 3;
  const int ch = blockIdx.y;
  const int i0 = blockIdx.x * 32;
  const __hip_bfloat16* v = dw + ((size_t)b * C3 + 2 * CC + hd * CH + ch) * HW;
  const float* A = attn + (size_t)bh * HH * HH;

  __shared__ float At[32][128];
  for (int t = threadIdx.x; t < 32 * 128; t += 256)
    At[t >> 7][t & 127] = A[(i0 + (t >> 7)) * HH + (t & 127)];
  __syncthreads();

  const int w = threadIdx.x & 127;
  const int ig = threadIdx.x >> 7;   // 0..1 -> 16 rows each
  float acc[16] = {};
  for (int j = 0; j < 128; ++j) {
    const float vv = __bfloat162float(v[j * WW + w]);
#pragma unroll
    for (int ii = 0; ii < 16; ++ii) acc[ii] += At[ig * 16 + ii][j] * vv;
  }
  float* ob = outc + ((size_t)b * CC + hd * CH + ch) * HW + w;
#pragma unroll
  for (int ii = 0; ii < 16; ++ii) ob[(size_t)(i0 + ig * 16 + ii) * WW] = acc[ii];
}

extern "C" void kernel_launch(void* const* d_in, const int* in_sizes, int n_in,
                              void* d_out, int out_size, void* d_ws, size_t ws_size,
                              hipStream_t stream) {
  const float* x     = (const float*)d_in[0];
  const float* wqkv  = (const float*)d_in[1];
  const float* wdw   = (const float*)d_in[2];
  const float* wproj = (const float*)d_in[3];
  const float* temp  = (const float*)d_in[4];

  char* ws = (char*)d_ws;
  __hip_bfloat16* qkvraw = (__hip_bfloat16*)(ws + OFF_RAW);
  __hip_bfloat16* qkvdw  = (__hip_bfloat16*)(ws + OFF_DW);
  float* sp   = (float*)(ws + OFF_SP);
  float* rq   = (float*)(ws + OFF_RQ);
  float* rk   = (float*)(ws + OFF_RK);
  float* attn = (float*)(ws + OFF_AT);
  float* aout = (float*)(ws + OFF_RAW);   // qkv_raw is dead after dwconv; reuse

  k_conv1x1<C3, __hip_bfloat16><<<dim3(HW / 64, C3 / 64, BB), 256, 0, stream>>>(x, wqkv, qkvraw);
  k_dwconv<<<dim3(HH / 2, C3, BB), 256, 0, stream>>>(qkvraw, wdw, qkvdw);
  k_norms<<<dim3(HH, NH, 2 * BB), 256, 0, stream>>>(qkvdw, rq, rk);
  k_qk<<<dim3(NFC, 2, BB * NH), 256, 0, stream>>>(qkvdw, sp);
  k_softmax<<<dim3(HH, BB * NH), 64, 0, stream>>>(sp, rq, rk, temp, attn);
  k_pv<<<dim3(HH / 32, CH, BB * NH), 256, 0, stream>>>(attn, qkvdw, aout);
  k_conv1x1<CC, float><<<dim3(HW / 64, CC / 64, BB), 256, 0, stream>>>(aout, wproj, (float*)d_out);
}

// Round 2
// 903.005 us; speedup vs baseline: 1.2910x; 1.2910x over previous
//
#include <hip/hip_runtime.h>
#include <hip/hip_bf16.h>

// Problem sizes
#define BB 8
#define CC 192
#define C3 576
#define NH 4
#define CH 48
#define HH 128
#define WW 128
#define HW 16384
#define FF 6144

typedef short s16x8 __attribute__((ext_vector_type(8)));
typedef float f32x4 __attribute__((ext_vector_type(4)));

constexpr int NFC = 12;                    // f-chunks for QK^T partials
constexpr size_t SPM = 32ull * 128 * 128;  // elems per partial-S chunk

// workspace layout (bytes)
constexpr size_t OFF_XT  = 0;                          // bf16 xT [8][16384][192]
constexpr size_t SZ_XT   = (size_t)BB * HW * CC * 2;
constexpr size_t OFF_WQ  = OFF_XT + SZ_XT;             // bf16 w_qkv [576][192]
constexpr size_t SZ_WQ   = (size_t)C3 * CC * 2;
constexpr size_t OFF_RAW = OFF_WQ + SZ_WQ;             // bf16 qkvraw; reused as fp32 aout
constexpr size_t SZ_RAW  = (size_t)BB * C3 * HW * 2;
constexpr size_t OFF_DW  = OFF_RAW + SZ_RAW;           // bf16 qkv post-dw
constexpr size_t OFF_SP  = OFF_DW + SZ_RAW;            // fp32 partial S
constexpr size_t OFF_RQ  = OFF_SP + (size_t)NFC * SPM * 4;
constexpr size_t OFF_RK  = OFF_RQ + 32 * 128 * 4;
constexpr size_t OFF_AT  = OFF_RK + 32 * 128 * 4;      // fp32 attn [32][128][128]

__device__ __forceinline__ void store_out(__hip_bfloat16* p, float v) { *p = __float2bfloat16(v); }
__device__ __forceinline__ void store_out(float* p, float v) { *p = v; }

__device__ __forceinline__ void gload16(const void* g, void* l) {
  __builtin_amdgcn_global_load_lds((const __attribute__((address_space(1))) unsigned int*)g,
                                   (__attribute__((address_space(3))) unsigned int*)l, 16, 0, 0);
}

// fp32 [b][C][P] -> bf16 [b][P][C] transpose+convert (tiles 32c x 64p)
__global__ __launch_bounds__(256) void k_cvt_t(const float* __restrict__ in,
                                               __hip_bfloat16* __restrict__ outT) {
  const int p0 = blockIdx.x * 64;
  const int c0 = blockIdx.y * 32;
  const int b = blockIdx.z;
  __shared__ float t[32][65];
  const float* ib = in + (size_t)b * CC * HW;
  const int tid = threadIdx.x;
  {
    const int c = tid >> 3, pl = (tid & 7) * 8;
    const float* s = ib + (size_t)(c0 + c) * HW + p0 + pl;
#pragma unroll
    for (int j = 0; j < 8; ++j) t[c][pl + j] = s[j];
  }
  __syncthreads();
  {
    const int pl = tid >> 2, cl = (tid & 3) * 8;
    __hip_bfloat16* d = outT + (size_t)b * HW * CC + (size_t)(p0 + pl) * CC + c0 + cl;
#pragma unroll
    for (int j = 0; j < 8; ++j) d[j] = __float2bfloat16(t[cl + j][pl]);
  }
}

__global__ __launch_bounds__(256) void k_cvt_w(const float* __restrict__ in,
                                               __hip_bfloat16* __restrict__ out, int n) {
  const int i = blockIdx.x * 256 + threadIdx.x;
  if (i < n) out[i] = __float2bfloat16(in[i]);
}

// MFMA bf16 GEMM: out[b][o][p] = sum_c W[o][c] * xT[b][p][c]
// BM=192 BN=128, 4 waves (2x2), K chunks of 32, fragment-linear LDS.
template <int M, typename OutT>
__global__ __launch_bounds__(256) void k_gemm(const __hip_bfloat16* __restrict__ xT,
                                              const __hip_bfloat16* __restrict__ Wb,
                                              OutT* __restrict__ out) {
  const int pBase = blockIdx.x * 128;
  const int mBase = blockIdx.y * 192;
  const int b = blockIdx.z;
  __shared__ __hip_bfloat16 Al[6144];  // 12 KB: [mf(12)][kg(4)][row(16)][8]
  __shared__ __hip_bfloat16 Bl[4096];  // 8 KB:  [nf(8)][kg(4)][col(16)][8]
  const int tid = threadIdx.x;
  const int wave = tid >> 6, lane = tid & 63;
  const int wm = wave >> 1, wn = wave & 1;  // wave tile 96x64
  const __hip_bfloat16* xb = xT + (size_t)b * HW * CC;
  char* Alc = (char*)Al;
  char* Blc = (char*)Bl;
  f32x4 acc[6][4] = {};

  for (int k0 = 0; k0 < CC; k0 += 32) {
#pragma unroll
    for (int is = 0; is < 3; ++is) {
      const int ci = is * 256 + tid;
      const int row = ci & 15, kg = (ci >> 4) & 3, mf = ci >> 6;
      gload16(Wb + (size_t)(mBase + mf * 16 + row) * CC + k0 + kg * 8,
              Alc + is * 4096 + wave * 1024);
    }
#pragma unroll
    for (int is = 0; is < 2; ++is) {
      const int ci = is * 256 + tid;
      const int col = ci & 15, kg = (ci >> 4) & 3, nf = ci >> 6;
      gload16(xb + (size_t)(pBase + nf * 16 + col) * CC + k0 + kg * 8,
              Blc + is * 4096 + wave * 1024);
    }
    __syncthreads();
    s16x8 a[6], bf[4];
#pragma unroll
    for (int i = 0; i < 6; ++i) a[i] = *(const s16x8*)(Alc + ((wm * 6 + i) << 10) + (lane << 4));
#pragma unroll
    for (int j = 0; j < 4; ++j) bf[j] = *(const s16x8*)(Blc + ((wn * 4 + j) << 10) + (lane << 4));
#pragma unroll
    for (int i = 0; i < 6; ++i)
#pragma unroll
      for (int j = 0; j < 4; ++j)
        acc[i][j] = __builtin_amdgcn_mfma_f32_16x16x32_bf16(a[i], bf[j], acc[i][j], 0, 0, 0);
    __syncthreads();
  }
  OutT* ob = out + (size_t)b * M * HW;
  const int r0 = (lane >> 4) * 4, cl = lane & 15;
#pragma unroll
  for (int i = 0; i < 6; ++i) {
    const int o = mBase + (wm * 6 + i) * 16 + r0;
#pragma unroll
    for (int j = 0; j < 4; ++j) {
      const int p = pBase + (wn * 4 + j) * 16 + cl;
      OutT* dst = ob + (size_t)o * HW + p;
#pragma unroll
      for (int r = 0; r < 4; ++r) store_out(dst + (size_t)r * HW, acc[i][j][r]);
    }
  }
}

// fp32 tiled GEMM (kept for proj): out[b,o,p] = sum_c wgt[o*192+c] * x[b,c,p]
template <int M, typename OutT>
__global__ __launch_bounds__(256) void k_conv1x1(const float* __restrict__ x,
                                                 const float* __restrict__ wgt,
                                                 OutT* __restrict__ out) {
  const int pBase = blockIdx.x * 64;
  const int oBase = blockIdx.y * 64;
  const int b = blockIdx.z;
  const float* xb = x + (size_t)b * CC * HW;
  OutT* ob = out + (size_t)b * M * HW;

  __shared__ float Wt[64][33];
  __shared__ float Xt[32][64];

  const int tid = threadIdx.x;
  const int tx = tid & 15;
  const int ty = tid >> 4;
  float acc[4][4] = {};

  for (int k0 = 0; k0 < CC; k0 += 32) {
    {
      const int o = tid >> 2;
      const int k = (tid & 3) * 8;
      const float* s = wgt + (size_t)(oBase + o) * CC + k0 + k;
#pragma unroll
      for (int j = 0; j < 8; ++j) Wt[o][k + j] = s[j];
    }
    {
      const int k = tid >> 3;
      const int p = (tid & 7) * 8;
      const float* s = xb + (size_t)(k0 + k) * HW + pBase + p;
#pragma unroll
      for (int j = 0; j < 8; ++j) Xt[k][p + j] = s[j];
    }
    __syncthreads();
#pragma unroll
    for (int k = 0; k < 32; ++k) {
      float a[4], bv[4];
#pragma unroll
      for (int i = 0; i < 4; ++i) a[i] = Wt[ty * 4 + i][k];
#pragma unroll
      for (int j = 0; j < 4; ++j) bv[j] = Xt[k][tx * 4 + j];
#pragma unroll
      for (int i = 0; i < 4; ++i)
#pragma unroll
        for (int j = 0; j < 4; ++j) acc[i][j] += a[i] * bv[j];
    }
    __syncthreads();
  }
#pragma unroll
  for (int i = 0; i < 4; ++i) {
    OutT* dst = ob + (size_t)(oBase + ty * 4 + i) * HW + pBase + tx * 4;
#pragma unroll
    for (int j = 0; j < 4; ++j) store_out(dst + j, acc[i][j]);
  }
}

// depthwise 3x3, pad 1
__global__ __launch_bounds__(256) void k_dwconv(const __hip_bfloat16* __restrict__ in,
                                                const float* __restrict__ wdw,
                                                __hip_bfloat16* __restrict__ out) {
  const int b = blockIdx.z;
  const int c = blockIdx.y;
  const int h = blockIdx.x * 2 + (threadIdx.x >> 7);
  const int w = threadIdx.x & 127;
  const __hip_bfloat16* src = in + ((size_t)b * C3 + c) * HW;
  const float* wp = wdw + c * 9;
  float acc = 0.f;
#pragma unroll
  for (int dh = -1; dh <= 1; ++dh) {
    const int hh = h + dh;
    if (hh < 0 || hh >= HH) continue;
#pragma unroll
    for (int dw = -1; dw <= 1; ++dw) {
      const int ww2 = w + dw;
      if (ww2 < 0 || ww2 >= WW) continue;
      acc += __bfloat162float(src[hh * WW + ww2]) * wp[(dh + 1) * 3 + (dw + 1)];
    }
  }
  out[((size_t)b * C3 + c) * HW + h * WW + w] = __float2bfloat16(acc);
}

// reciprocal L2 norms of q,k rows
__global__ __launch_bounds__(256) void k_norms(const __hip_bfloat16* __restrict__ dw,
                                               float* __restrict__ rq, float* __restrict__ rk) {
  const int i = blockIdx.x;
  const int hd = blockIdx.y;
  const int b = blockIdx.z & 7;
  const int which = blockIdx.z >> 3;
  const __hip_bfloat16* base = dw + ((size_t)b * C3 + which * CC + hd * CH) * HW + i * WW;
  float s = 0.f;
  for (int t = threadIdx.x; t < FF; t += 256) {
    const int ch = t >> 7, w = t & 127;
    const float v = __bfloat162float(base[(size_t)ch * HW + w]);
    s += v * v;
  }
  __shared__ float red[4];
  const int lane = threadIdx.x & 63, wv = threadIdx.x >> 6;
#pragma unroll
  for (int off = 32; off > 0; off >>= 1) s += __shfl_down(s, off);
  if (lane == 0) red[wv] = s;
  __syncthreads();
  if (threadIdx.x == 0) {
    const float n = sqrtf(red[0] + red[1] + red[2] + red[3]);
    float* dst = which ? rk : rq;
    dst[(b * NH + hd) * HH + i] = 1.f / fmaxf(n, 1e-12f);
  }
}

// partial S over a 512-feature chunk
__global__ __launch_bounds__(256) void k_qk(const __hip_bfloat16* __restrict__ dw,
                                            float* __restrict__ sp) {
  const int fc = blockIdx.x;
  const int i0 = blockIdx.y * 64;
  const int bh = blockIdx.z;
  const int b = bh >> 2, hd = bh & 3;
  const __hip_bfloat16* qb = dw + ((size_t)b * C3 + hd * CH + fc * 4) * HW;
  const __hip_bfloat16* kb = qb + (size_t)CC * HW;

  __shared__ float Qt[16][64];
  __shared__ float Kt[16][128];

  const int tid = threadIdx.x;
  const int tx = tid & 15;
  const int ty = tid >> 4;
  float acc[4][8] = {};

  for (int kc = 0; kc < 32; ++kc) {
    const int chl = kc >> 3;
    const int w0 = (kc & 7) * 16;
    {
      const int i = tid >> 2;
      const int kf0 = (tid & 3) * 4;
      const __hip_bfloat16* s = qb + (size_t)chl * HW + (i0 + i) * WW + w0 + kf0;
#pragma unroll
      for (int j = 0; j < 4; ++j) Qt[kf0 + j][i] = __bfloat162float(s[j]);
    }
    {
      const int jj = tid >> 1;
      const int kf0 = (tid & 1) * 8;
      const __hip_bfloat16* s = kb + (size_t)chl * HW + jj * WW + w0 + kf0;
#pragma unroll
      for (int j = 0; j < 8; ++j) Kt[kf0 + j][jj] = __bfloat162float(s[j]);
    }
    __syncthreads();
#pragma unroll
    for (int kf = 0; kf < 16; ++kf) {
      float a[4], bv[8];
#pragma unroll
      for (int ii = 0; ii < 4; ++ii) a[ii] = Qt[kf][ty * 4 + ii];
#pragma unroll
      for (int jj = 0; jj < 8; ++jj) bv[jj] = Kt[kf][tx * 8 + jj];
#pragma unroll
      for (int ii = 0; ii < 4; ++ii)
#pragma unroll
        for (int jj = 0; jj < 8; ++jj) acc[ii][jj] += a[ii] * bv[jj];
    }
    __syncthreads();
  }
  float* o = sp + (size_t)fc * SPM + ((size_t)bh * HH + i0) * HH;
#pragma unroll
  for (int ii = 0; ii < 4; ++ii)
#pragma unroll
    for (int jj = 0; jj < 8; ++jj)
      o[(ty * 4 + ii) * HH + tx * 8 + jj] = acc[ii][jj];
}

// reduce partials, scale, softmax
__global__ __launch_bounds__(64) void k_softmax(const float* __restrict__ sp,
                                                const float* __restrict__ rq,
                                                const float* __restrict__ rk,
                                                const float* __restrict__ temp,
                                                float* __restrict__ attn) {
  const int i = blockIdx.x;
  const int bh = blockIdx.y;
  const int hd = bh & 3;
  const int lane = threadIdx.x;
  const size_t rowoff = ((size_t)bh * HH + i) * HH;
  float s0 = 0.f, s1 = 0.f;
#pragma unroll
  for (int fc = 0; fc < NFC; ++fc) {
    s0 += sp[fc * SPM + rowoff + lane];
    s1 += sp[fc * SPM + rowoff + lane + 64];
  }
  const float scale = rq[bh * HH + i] * temp[hd];
  s0 *= scale * rk[bh * HH + lane];
  s1 *= scale * rk[bh * HH + lane + 64];
  float m = fmaxf(s0, s1);
#pragma unroll
  for (int off = 32; off > 0; off >>= 1) m = fmaxf(m, __shfl_xor(m, off));
  const float e0 = expf(s0 - m), e1 = expf(s1 - m);
  float ssum = e0 + e1;
#pragma unroll
  for (int off = 32; off > 0; off >>= 1) ssum += __shfl_xor(ssum, off);
  const float inv = 1.f / ssum;
  attn[rowoff + lane] = e0 * inv;
  attn[rowoff + lane + 64] = e1 * inv;
}

// out[b, hd*48+ch, i, w] = sum_j attn[bh,i,j] * v[b, 384+hd*48+ch, j, w]
__global__ __launch_bounds__(256) void k_pv(const float* __restrict__ attn,
                                            const __hip_bfloat16* __restrict__ dw,
                                            float* __restrict__ outc) {
  const int bh = blockIdx.z;
  const int b = bh >> 2, hd = bh & 3;
  const int ch = blockIdx.y;
  const int i0 = blockIdx.x * 32;
  const __hip_bfloat16* v = dw + ((size_t)b * C3 + 2 * CC + hd * CH + ch) * HW;
  const float* A = attn + (size_t)bh * HH * HH;

  __shared__ float At[32][128];
  for (int t = threadIdx.x; t < 32 * 128; t += 256)
    At[t >> 7][t & 127] = A[(i0 + (t >> 7)) * HH + (t & 127)];
  __syncthreads();

  const int w = threadIdx.x & 127;
  const int ig = threadIdx.x >> 7;
  float acc[16] = {};
  for (int j = 0; j < 128; ++j) {
    const float vv = __bfloat162float(v[j * WW + w]);
#pragma unroll
    for (int ii = 0; ii < 16; ++ii) acc[ii] += At[ig * 16 + ii][j] * vv;
  }
  float* ob = outc + ((size_t)b * CC + hd * CH + ch) * HW + w;
#pragma unroll
  for (int ii = 0; ii < 16; ++ii) ob[(size_t)(i0 + ig * 16 + ii) * WW] = acc[ii];
}

extern "C" void kernel_launch(void* const* d_in, const int* in_sizes, int n_in,
                              void* d_out, int out_size, void* d_ws, size_t ws_size,
                              hipStream_t stream) {
  const float* x     = (const float*)d_in[0];
  const float* wqkv  = (const float*)d_in[1];
  const float* wdw   = (const float*)d_in[2];
  const float* wproj = (const float*)d_in[3];
  const float* temp  = (const float*)d_in[4];

  char* ws = (char*)d_ws;
  __hip_bfloat16* xTb    = (__hip_bfloat16*)(ws + OFF_XT);
  __hip_bfloat16* Wq     = (__hip_bfloat16*)(ws + OFF_WQ);
  __hip_bfloat16* qkvraw = (__hip_bfloat16*)(ws + OFF_RAW);
  __hip_bfloat16* qkvdw  = (__hip_bfloat16*)(ws + OFF_DW);
  float* sp   = (float*)(ws + OFF_SP);
  float* rq   = (float*)(ws + OFF_RQ);
  float* rk   = (float*)(ws + OFF_RK);
  float* attn = (float*)(ws + OFF_AT);
  float* aout = (float*)(ws + OFF_RAW);   // qkvraw dead after dwconv; reuse

  k_cvt_w<<<dim3((C3 * CC + 255) / 256), 256, 0, stream>>>(wqkv, Wq, C3 * CC);
  k_cvt_t<<<dim3(HW / 64, CC / 32, BB), 256, 0, stream>>>(x, xTb);
  k_gemm<C3, __hip_bfloat16><<<dim3(HW / 128, 3, BB), 256, 0, stream>>>(xTb, Wq, qkvraw);
  k_dwconv<<<dim3(HH / 2, C3, BB), 256, 0, stream>>>(qkvraw, wdw, qkvdw);
  k_norms<<<dim3(HH, NH, 2 * BB), 256, 0, stream>>>(qkvdw, rq, rk);
  k_qk<<<dim3(NFC, 2, BB * NH), 256, 0, stream>>>(qkvdw, sp);
  k_softmax<<<dim3(HH, BB * NH), 64, 0, stream>>>(sp, rq, rk, temp, attn);
  k_pv<<<dim3(HH / 32, CH, BB * NH), 256, 0, stream>>>(attn, qkvdw, aout);
  k_conv1x1<CC, float><<<dim3(HW / 64, CC / 64, BB), 256, 0, stream>>>(aout, wproj, (float*)d_out);
}

// Round 3
// 303.364 us; speedup vs baseline: 3.8427x; 2.9766x over previous
//
#include <hip/hip_runtime.h>
#include <hip/hip_bf16.h>

// Problem sizes
#define BB 8
#define CC 192
#define C3 576
#define NH 4
#define CH 48
#define HH 128
#define WW 128
#define HW 16384
#define FF 6144

typedef short s16x8 __attribute__((ext_vector_type(8)));
typedef float f32x4 __attribute__((ext_vector_type(4)));

constexpr size_t SPM = 32ull * 128 * 128;  // elems per partial-S chunk (fp32)

// workspace layout (bytes)
constexpr size_t OFF_XT  = 0;                           // bf16 xT [8][16384][192]; later vT [32][6144][128]
constexpr size_t SZ_XT   = (size_t)BB * HW * CC * 2;    // 50,331,648
constexpr size_t OFF_WQ  = OFF_XT + SZ_XT;              // bf16 w_qkv [576][192]
constexpr size_t SZ_WQ   = (size_t)C3 * CC * 2;
constexpr size_t OFF_WP  = OFF_WQ + SZ_WQ;              // bf16 w_proj [192][192]
constexpr size_t SZ_WP   = (size_t)CC * CC * 2;
constexpr size_t OFF_RAW = OFF_WP + SZ_WP;              // bf16 qkvraw; later pvout(+0), aT(+SZ_XT)
constexpr size_t SZ_RAW  = (size_t)BB * C3 * HW * 2;    // 150,994,944
constexpr size_t OFF_DW  = OFF_RAW + SZ_RAW;            // bf16 qkv post-dw (q,k sections used)
constexpr size_t OFF_SP  = OFF_DW + SZ_RAW;             // fp32 partial S [8][32][128][128]
constexpr size_t OFF_ATB = OFF_SP + 8 * SPM * 4;        // bf16 attn [32][128][128]
constexpr size_t OFF_RQ  = OFF_ATB + 32ull * 128 * 128 * 2;
constexpr size_t OFF_RK  = OFF_RQ + 32 * 128 * 4;

__device__ __forceinline__ void store_out(__hip_bfloat16* p, float v) { *p = __float2bfloat16(v); }
__device__ __forceinline__ void store_out(float* p, float v) { *p = v; }

__device__ __forceinline__ short bf16bits(float v) {
  __hip_bfloat16 t = __float2bfloat16(v);
  return *reinterpret_cast<short*>(&t);
}
__device__ __forceinline__ float b2f(short u) {
  union { unsigned int i; float f; } x;
  x.i = ((unsigned int)(unsigned short)u) << 16;
  return x.f;
}

__device__ __forceinline__ void gload16(const void* g, void* l) {
  __builtin_amdgcn_global_load_lds((const __attribute__((address_space(1))) unsigned int*)g,
                                   (__attribute__((address_space(3))) unsigned int*)l, 16, 0, 0);
}

// fp32 [b][C][P] -> bf16 [b][P][C] transpose+convert (tiles 32c x 64p)
__global__ __launch_bounds__(256) void k_cvt_t(const float* __restrict__ in,
                                               __hip_bfloat16* __restrict__ outT) {
  const int p0 = blockIdx.x * 64;
  const int c0 = blockIdx.y * 32;
  const int b = blockIdx.z;
  __shared__ float t[32][65];
  const float* ib = in + (size_t)b * CC * HW;
  const int tid = threadIdx.x;
  {
    const int c = tid >> 3, pl = (tid & 7) * 8;
    const float* s = ib + (size_t)(c0 + c) * HW + p0 + pl;
#pragma unroll
    for (int j = 0; j < 8; ++j) t[c][pl + j] = s[j];
  }
  __syncthreads();
  {
    const int pl = tid >> 2, cl = (tid & 3) * 8;
    __hip_bfloat16* d = outT + (size_t)b * HW * CC + (size_t)(p0 + pl) * CC + c0 + cl;
#pragma unroll
    for (int j = 0; j < 8; ++j) d[j] = __float2bfloat16(t[cl + j][pl]);
  }
}

__global__ __launch_bounds__(256) void k_cvt_w(const float* __restrict__ in,
                                               __hip_bfloat16* __restrict__ out, int n) {
  const int i = blockIdx.x * 256 + threadIdx.x;
  if (i < n) out[i] = __float2bfloat16(in[i]);
}

// MFMA bf16 GEMM: out[b][o][p] = sum_c W[o][c] * xT[b][p][c]
// BM=192 BN=128, 4 waves (2x2), K chunks of 32, fragment-linear LDS. (validated r2)
template <int M, typename OutT>
__global__ __launch_bounds__(256) void k_gemm(const __hip_bfloat16* __restrict__ xT,
                                              const __hip_bfloat16* __restrict__ Wb,
                                              OutT* __restrict__ out) {
  const int pBase = blockIdx.x * 128;
  const int mBase = blockIdx.y * 192;
  const int b = blockIdx.z;
  __shared__ __hip_bfloat16 Al[6144];  // [mf(12)][kg(4)][row(16)][8]
  __shared__ __hip_bfloat16 Bl[4096];  // [nf(8)][kg(4)][col(16)][8]
  const int tid = threadIdx.x;
  const int wave = tid >> 6, lane = tid & 63;
  const int wm = wave >> 1, wn = wave & 1;
  const __hip_bfloat16* xb = xT + (size_t)b * HW * CC;
  char* Alc = (char*)Al;
  char* Blc = (char*)Bl;
  f32x4 acc[6][4] = {};

  for (int k0 = 0; k0 < CC; k0 += 32) {
#pragma unroll
    for (int is = 0; is < 3; ++is) {
      const int ci = is * 256 + tid;
      const int row = ci & 15, kg = (ci >> 4) & 3, mf = ci >> 6;
      gload16(Wb + (size_t)(mBase + mf * 16 + row) * CC + k0 + kg * 8,
              Alc + is * 4096 + wave * 1024);
    }
#pragma unroll
    for (int is = 0; is < 2; ++is) {
      const int ci = is * 256 + tid;
      const int col = ci & 15, kg = (ci >> 4) & 3, nf = ci >> 6;
      gload16(xb + (size_t)(pBase + nf * 16 + col) * CC + k0 + kg * 8,
              Blc + is * 4096 + wave * 1024);
    }
    __syncthreads();
    s16x8 a[6], bf[4];
#pragma unroll
    for (int i = 0; i < 6; ++i) a[i] = *(const s16x8*)(Alc + ((wm * 6 + i) << 10) + (lane << 4));
#pragma unroll
    for (int j = 0; j < 4; ++j) bf[j] = *(const s16x8*)(Blc + ((wn * 4 + j) << 10) + (lane << 4));
#pragma unroll
    for (int i = 0; i < 6; ++i)
#pragma unroll
      for (int j = 0; j < 4; ++j)
        acc[i][j] = __builtin_amdgcn_mfma_f32_16x16x32_bf16(a[i], bf[j], acc[i][j], 0, 0, 0);
    __syncthreads();
  }
  OutT* ob = out + (size_t)b * M * HW;
  const int r0 = (lane >> 4) * 4, cl = lane & 15;
#pragma unroll
  for (int i = 0; i < 6; ++i) {
    const int o = mBase + (wm * 6 + i) * 16 + r0;
#pragma unroll
    for (int j = 0; j < 4; ++j) {
      const int p = pBase + (wn * 4 + j) * 16 + cl;
      OutT* dst = ob + (size_t)o * HW + p;
#pragma unroll
      for (int r = 0; r < 4; ++r) store_out(dst + (size_t)r * HW, acc[i][j][r]);
    }
  }
}

// depthwise 3x3 pad 1, vectorized; V channels are written TRANSPOSED to vt[f][j]
__global__ __launch_bounds__(256) void k_dwconv(const __hip_bfloat16* __restrict__ in,
                                                const float* __restrict__ wdw,
                                                __hip_bfloat16* __restrict__ out,
                                                __hip_bfloat16* __restrict__ vt) {
  const int h0 = blockIdx.x * 32;
  const int c = blockIdx.y;
  const int b = blockIdx.z;
  __shared__ __hip_bfloat16 IN[34][136];  // pad 8 -> row 272B, bank-spread
  __shared__ char TR[8192];               // swizzled [w 128][h 32] bf16
  const int tid = threadIdx.x;
  const __hip_bfloat16* src = in + ((size_t)b * C3 + c) * HW;
#pragma unroll
  for (int it = 0; it < 3; ++it) {
    const int vi = it * 256 + tid;
    if (vi < 544) {
      const int r = vi >> 4, w8 = vi & 15;
      const int hg = h0 - 1 + r;
      s16x8 v = {};
      if (hg >= 0 && hg < HH) v = *(const s16x8*)(src + (size_t)hg * WW + w8 * 8);
      *(s16x8*)(&IN[r][w8 * 8]) = v;
    }
  }
  const float* wp = wdw + c * 9;
  float wgt[9];
#pragma unroll
  for (int q = 0; q < 9; ++q) wgt[q] = wp[q];
  __syncthreads();

  const int hl = tid >> 3, w0 = (tid & 7) * 16;
  float rowv[3][18];
#pragma unroll
  for (int dh = 0; dh < 3; ++dh)
#pragma unroll
    for (int e = 0; e < 18; ++e) {
      const int w = w0 - 1 + e;
      rowv[dh][e] = (w >= 0 && w < WW) ? __bfloat162float(IN[hl + dh][w]) : 0.f;
    }
  float res[16];
#pragma unroll
  for (int ww = 0; ww < 16; ++ww) {
    float acc = 0.f;
#pragma unroll
    for (int dh = 0; dh < 3; ++dh)
#pragma unroll
      for (int dwi = 0; dwi < 3; ++dwi)
        acc += rowv[dh][ww + dwi] * wgt[dh * 3 + dwi];
    res[ww] = acc;
  }
  if (c < 2 * CC) {  // q,k: natural layout
    short pk[16];
#pragma unroll
    for (int ww = 0; ww < 16; ++ww) pk[ww] = bf16bits(res[ww]);
    __hip_bfloat16* dst = out + ((size_t)b * C3 + c) * HW + (size_t)(h0 + hl) * WW + w0;
    *(s16x8*)dst = *(const s16x8*)pk;
    *(s16x8*)(dst + 8) = *(const s16x8*)(pk + 8);
  } else {  // v: LDS transpose -> vt[(b*4+hd)][ch*128+w][h]
    const int rel = c - 2 * CC;
    const int hd = rel / CH, ch = rel - hd * CH;
#pragma unroll
    for (int ww = 0; ww < 16; ++ww) {
      const int w = w0 + ww;
      const int blk = ((w << 2) + (hl >> 3)) ^ ((w >> 3) & 3);
      *(short*)(TR + (blk << 4) + ((hl & 7) << 1)) = bf16bits(res[ww]);
    }
    __syncthreads();
    const int w = tid >> 1, half = tid & 1;
    short ot[16];
#pragma unroll
    for (int j = 0; j < 2; ++j) {
      const int hh = half * 16 + j * 8;
      const int blk = ((w << 2) + (hh >> 3)) ^ ((w >> 3) & 3);
      *(s16x8*)(ot + j * 8) = *(const s16x8*)(TR + (blk << 4));
    }
    __hip_bfloat16* vd = vt + ((size_t)(b * NH + hd) * FF + (size_t)ch * WW + w) * HH + h0 + half * 16;
    *(s16x8*)vd = *(const s16x8*)ot;
    *(s16x8*)(vd + 8) = *(const s16x8*)(ot + 8);
  }
}

// reciprocal L2 norms of q,k rows (vectorized)
__global__ __launch_bounds__(256) void k_norms(const __hip_bfloat16* __restrict__ dw,
                                               float* __restrict__ rq, float* __restrict__ rk) {
  const int i = blockIdx.x;
  const int hd = blockIdx.y;
  const int b = blockIdx.z & 7;
  const int which = blockIdx.z >> 3;
  const __hip_bfloat16* base = dw + ((size_t)b * C3 + which * CC + hd * CH) * HW + i * WW;
  float s = 0.f;
#pragma unroll
  for (int it = 0; it < 3; ++it) {
    const int idx = it * 256 + threadIdx.x;
    const int ch = idx >> 4, w8 = idx & 15;
    const s16x8 v = *(const s16x8*)(base + (size_t)ch * HW + w8 * 8);
#pragma unroll
    for (int e = 0; e < 8; ++e) {
      const float f = b2f(v[e]);
      s += f * f;
    }
  }
  __shared__ float red[4];
  const int lane = threadIdx.x & 63, wv = threadIdx.x >> 6;
#pragma unroll
  for (int off = 32; off > 0; off >>= 1) s += __shfl_down(s, off);
  if (lane == 0) red[wv] = s;
  __syncthreads();
  if (threadIdx.x == 0) {
    const float n = sqrtf(red[0] + red[1] + red[2] + red[3]);
    float* dst = which ? rk : rq;
    dst[(b * NH + hd) * HH + i] = 1.f / fmaxf(n, 1e-12f);
  }
}

// MFMA QK^T partials: sp[ks][bh][i][j], K-split 8 x 768
__global__ __launch_bounds__(256) void k_qkm(const __hip_bfloat16* __restrict__ dw,
                                             float* __restrict__ sp) {
  const int ks = blockIdx.x;
  const int bh = blockIdx.y;
  const int b = bh >> 2, hd = bh & 3;
  const __hip_bfloat16* qb = dw + ((size_t)b * C3 + hd * CH) * HW;
  const __hip_bfloat16* kb = dw + ((size_t)b * C3 + CC + hd * CH) * HW;
  __shared__ __hip_bfloat16 Al[4096];
  __shared__ __hip_bfloat16 Bl[4096];
  char* Alc = (char*)Al;
  char* Blc = (char*)Bl;
  const int tid = threadIdx.x, wave = tid >> 6, lane = tid & 63;
  const int wm = wave >> 1, wn = wave & 1;
  f32x4 acc[4][4] = {};
  for (int chunk = 0; chunk < 24; ++chunk) {
    const int ch = ks * 6 + (chunk >> 2);
    const int w0 = (chunk & 3) * 32;
#pragma unroll
    for (int is = 0; is < 2; ++is) {
      const int ci = is * 256 + tid;
      const int row = ci & 15, kg = (ci >> 4) & 3, mf = ci >> 6;
      gload16(qb + (size_t)ch * HW + (mf * 16 + row) * WW + w0 + kg * 8,
              Alc + is * 4096 + wave * 1024);
    }
#pragma unroll
    for (int is = 0; is < 2; ++is) {
      const int ci = is * 256 + tid;
      const int col = ci & 15, kg = (ci >> 4) & 3, nf = ci >> 6;
      gload16(kb + (size_t)ch * HW + (nf * 16 + col) * WW + w0 + kg * 8,
              Blc + is * 4096 + wave * 1024);
    }
    __syncthreads();
    s16x8 a[4], bf[4];
#pragma unroll
    for (int i = 0; i < 4; ++i) a[i] = *(const s16x8*)(Alc + ((wm * 4 + i) << 10) + (lane << 4));
#pragma unroll
    for (int j = 0; j < 4; ++j) bf[j] = *(const s16x8*)(Blc + ((wn * 4 + j) << 10) + (lane << 4));
#pragma unroll
    for (int i = 0; i < 4; ++i)
#pragma unroll
      for (int j = 0; j < 4; ++j)
        acc[i][j] = __builtin_amdgcn_mfma_f32_16x16x32_bf16(a[i], bf[j], acc[i][j], 0, 0, 0);
    __syncthreads();
  }
  float* o = sp + (size_t)ks * SPM + (size_t)bh * HH * HH;
  const int r0 = (lane >> 4) * 4, cl = lane & 15;
#pragma unroll
  for (int i = 0; i < 4; ++i)
#pragma unroll
    for (int j = 0; j < 4; ++j) {
      const int ii = wm * 64 + i * 16 + r0;
      const int jj = wn * 64 + j * 16 + cl;
#pragma unroll
      for (int r = 0; r < 4; ++r) o[(ii + r) * HH + jj] = acc[i][j][r];
    }
}

// reduce partials, scale, softmax -> bf16 attn
__global__ __launch_bounds__(64) void k_softmax(const float* __restrict__ sp,
                                                const float* __restrict__ rq,
                                                const float* __restrict__ rk,
                                                const float* __restrict__ temp,
                                                __hip_bfloat16* __restrict__ atb) {
  const int i = blockIdx.x;
  const int bh = blockIdx.y;
  const int hd = bh & 3;
  const int lane = threadIdx.x;
  const size_t rowoff = ((size_t)bh * HH + i) * HH;
  float s0 = 0.f, s1 = 0.f;
#pragma unroll
  for (int ks = 0; ks < 8; ++ks) {
    s0 += sp[ks * SPM + rowoff + lane];
    s1 += sp[ks * SPM + rowoff + lane + 64];
  }
  const float scale = rq[bh * HH + i] * temp[hd];
  s0 *= scale * rk[bh * HH + lane];
  s1 *= scale * rk[bh * HH + lane + 64];
  float m = fmaxf(s0, s1);
#pragma unroll
  for (int off = 32; off > 0; off >>= 1) m = fmaxf(m, __shfl_xor(m, off));
  const float e0 = expf(s0 - m), e1 = expf(s1 - m);
  float ssum = e0 + e1;
#pragma unroll
  for (int off = 32; off > 0; off >>= 1) ssum += __shfl_xor(ssum, off);
  const float inv = 1.f / ssum;
  atb[rowoff + lane] = __float2bfloat16(e0 * inv);
  atb[rowoff + lane + 64] = __float2bfloat16(e1 * inv);
}

// MFMA PV: pvout[bh][i][f] = sum_j attn[bh][i][j] * vt[bh][f][j]
__global__ __launch_bounds__(256) void k_pvm(const __hip_bfloat16* __restrict__ atb,
                                             const __hip_bfloat16* __restrict__ vt,
                                             __hip_bfloat16* __restrict__ pvout) {
  const int fs = blockIdx.x;  // 0..23 (256 f each)
  const int bh = blockIdx.y;
  const __hip_bfloat16* ab = atb + (size_t)bh * HH * HH;
  const __hip_bfloat16* vb = vt + ((size_t)bh * FF + fs * 256) * HH;
  __shared__ __hip_bfloat16 Al[4096];   // 8KB  A chunk
  __shared__ __hip_bfloat16 Bl[8192];   // 16KB B chunk
  char* Alc = (char*)Al;
  char* Blc = (char*)Bl;
  const int tid = threadIdx.x, wave = tid >> 6, lane = tid & 63;
  const int wm = wave >> 1, wn = wave & 1;
  f32x4 acc[4][8] = {};
  for (int kc = 0; kc < 4; ++kc) {
    const int kj0 = kc * 32;
#pragma unroll
    for (int is = 0; is < 2; ++is) {
      const int ci = is * 256 + tid;
      const int row = ci & 15, kg = (ci >> 4) & 3, mf = ci >> 6;
      gload16(ab + (size_t)(mf * 16 + row) * HH + kj0 + kg * 8,
              Alc + is * 4096 + wave * 1024);
    }
#pragma unroll
    for (int is = 0; is < 4; ++is) {
      const int ci = is * 256 + tid;
      const int col = ci & 15, kg = (ci >> 4) & 3, nf = ci >> 6;
      gload16(vb + (size_t)(nf * 16 + col) * HH + kj0 + kg * 8,
              Blc + is * 4096 + wave * 1024);
    }
    __syncthreads();
    s16x8 a[4], bf[8];
#pragma unroll
    for (int i = 0; i < 4; ++i) a[i] = *(const s16x8*)(Alc + ((wm * 4 + i) << 10) + (lane << 4));
#pragma unroll
    for (int j = 0; j < 8; ++j) bf[j] = *(const s16x8*)(Blc + ((wn * 8 + j) << 10) + (lane << 4));
#pragma unroll
    for (int i = 0; i < 4; ++i)
#pragma unroll
      for (int j = 0; j < 8; ++j)
        acc[i][j] = __builtin_amdgcn_mfma_f32_16x16x32_bf16(a[i], bf[j], acc[i][j], 0, 0, 0);
    __syncthreads();
  }
  __hip_bfloat16* ob = pvout + (size_t)bh * HH * FF;
  const int r0 = (lane >> 4) * 4, cl = lane & 15;
#pragma unroll
  for (int i = 0; i < 4; ++i)
#pragma unroll
    for (int j = 0; j < 8; ++j) {
      const int ii = wm * 64 + i * 16 + r0;
      const int f = fs * 256 + wn * 128 + j * 16 + cl;
#pragma unroll
      for (int r = 0; r < 4; ++r) ob[(size_t)(ii + r) * FF + f] = __float2bfloat16(acc[i][j][r]);
    }
}

// transpose pvout [b][hd][i][ch*128+w] -> aT [b][i*128+w][hd*48+ch]
__global__ __launch_bounds__(256) void k_t2(const __hip_bfloat16* __restrict__ pvout,
                                            __hip_bfloat16* __restrict__ aT) {
  const int i = blockIdx.x;
  const int b = blockIdx.y;
  __shared__ char L[49152];  // [c 192][w 128] bf16, 16B-block XOR swizzled
  const int tid = threadIdx.x;
#pragma unroll
  for (int it = 0; it < 12; ++it) {
    const int vi = it * 256 + tid;
    const int c = vi >> 4, w8 = vi & 15;
    const int hd = c / CH, ch = c - hd * CH;
    const s16x8 v = *(const s16x8*)(pvout + ((size_t)(b * NH + hd) * HH + i) * FF + ch * 128 + w8 * 8);
    const int blk = ((c << 4) + w8) ^ ((c >> 3) & 7);
    *(s16x8*)(L + (blk << 4)) = v;
  }
  __syncthreads();
#pragma unroll
  for (int it = 0; it < 12; ++it) {
    const int vi = it * 256 + tid;
    const int w = vi / 24, c8 = vi - w * 24;
    short tmp[8];
#pragma unroll
    for (int e = 0; e < 8; ++e) {
      const int c = c8 * 8 + e;
      const int blk = ((c << 4) + (w >> 3)) ^ ((c >> 3) & 7);
      tmp[e] = *(const short*)(L + (blk << 4) + ((w & 7) << 1));
    }
    *(s16x8*)(aT + ((size_t)b * HW + (size_t)i * 128 + w) * CC + c8 * 8) = *(const s16x8*)tmp;
  }
}

extern "C" void kernel_launch(void* const* d_in, const int* in_sizes, int n_in,
                              void* d_out, int out_size, void* d_ws, size_t ws_size,
                              hipStream_t stream) {
  const float* x     = (const float*)d_in[0];
  const float* wqkv  = (const float*)d_in[1];
  const float* wdw   = (const float*)d_in[2];
  const float* wproj = (const float*)d_in[3];
  const float* temp  = (const float*)d_in[4];

  char* ws = (char*)d_ws;
  __hip_bfloat16* xTb    = (__hip_bfloat16*)(ws + OFF_XT);
  __hip_bfloat16* vt     = (__hip_bfloat16*)(ws + OFF_XT);          // xT dead after k_gemm
  __hip_bfloat16* Wq     = (__hip_bfloat16*)(ws + OFF_WQ);
  __hip_bfloat16* Wp     = (__hip_bfloat16*)(ws + OFF_WP);
  __hip_bfloat16* qkvraw = (__hip_bfloat16*)(ws + OFF_RAW);
  __hip_bfloat16* pvout  = (__hip_bfloat16*)(ws + OFF_RAW);         // qkvraw dead after dwconv
  __hip_bfloat16* aTb    = (__hip_bfloat16*)(ws + OFF_RAW + SZ_XT);
  __hip_bfloat16* qkvdw  = (__hip_bfloat16*)(ws + OFF_DW);
  float* sp   = (float*)(ws + OFF_SP);
  __hip_bfloat16* atb = (__hip_bfloat16*)(ws + OFF_ATB);
  float* rq   = (float*)(ws + OFF_RQ);
  float* rk   = (float*)(ws + OFF_RK);

  k_cvt_w<<<dim3((C3 * CC + 255) / 256), 256, 0, stream>>>(wqkv, Wq, C3 * CC);
  k_cvt_w<<<dim3((CC * CC + 255) / 256), 256, 0, stream>>>(wproj, Wp, CC * CC);
  k_cvt_t<<<dim3(HW / 64, CC / 32, BB), 256, 0, stream>>>(x, xTb);
  k_gemm<C3, __hip_bfloat16><<<dim3(HW / 128, 3, BB), 256, 0, stream>>>(xTb, Wq, qkvraw);
  k_dwconv<<<dim3(HH / 32, C3, BB), 256, 0, stream>>>(qkvraw, wdw, qkvdw, vt);
  k_norms<<<dim3(HH, NH, 2 * BB), 256, 0, stream>>>(qkvdw, rq, rk);
  k_qkm<<<dim3(8, 32), 256, 0, stream>>>(qkvdw, sp);
  k_softmax<<<dim3(HH, 32), 64, 0, stream>>>(sp, rq, rk, temp, atb);
  k_pvm<<<dim3(24, 32), 256, 0, stream>>>(atb, vt, pvout);
  k_t2<<<dim3(HH, BB), 256, 0, stream>>>(pvout, aTb);
  k_gemm<CC, float><<<dim3(HW / 128, 1, BB), 256, 0, stream>>>(aTb, Wp, (float*)d_out);
}

// Round 4
// 284.819 us; speedup vs baseline: 4.0929x; 1.0651x over previous
//
#include <hip/hip_runtime.h>
#include <hip/hip_bf16.h>

// Problem sizes
#define BB 8
#define CC 192
#define C3 576
#define NH 4
#define CH 48
#define HH 128
#define WW 128
#define HW 16384
#define FF 6144

typedef short s16x8 __attribute__((ext_vector_type(8)));
typedef float f32x4 __attribute__((ext_vector_type(4)));

constexpr size_t SPM = 32ull * 128 * 128;  // elems per partial-S chunk (fp32)

// workspace layout (bytes)
constexpr size_t OFF_XT  = 0;                           // bf16 xT [8][16384][192]; later vT [32][6144][128]
constexpr size_t SZ_XT   = (size_t)BB * HW * CC * 2;
constexpr size_t OFF_WQ  = OFF_XT + SZ_XT;              // bf16 w_qkv [576][192]
constexpr size_t SZ_WQ   = (size_t)C3 * CC * 2;
constexpr size_t OFF_WP  = OFF_WQ + SZ_WQ;              // bf16 w_proj [192][192]
constexpr size_t SZ_WP   = (size_t)CC * CC * 2;
constexpr size_t OFF_RAW = OFF_WP + SZ_WP;              // bf16 qkvraw; later pvout
constexpr size_t SZ_RAW  = (size_t)BB * C3 * HW * 2;
constexpr size_t OFF_DW  = OFF_RAW + SZ_RAW;            // bf16 qkv post-dw (q,k used)
constexpr size_t OFF_SP  = OFF_DW + SZ_RAW;             // fp32 partial S [8][32][128][128]; psum aliased at front
constexpr size_t OFF_ATB = OFF_SP + 8 * SPM * 4;        // bf16 attn [32][128][128]
constexpr size_t OFF_RQ  = OFF_ATB + 32ull * 128 * 128 * 2;
constexpr size_t OFF_RK  = OFF_RQ + 32 * 128 * 4;
constexpr size_t OFF_PS  = OFF_SP;                      // fp32 psum [8][128][384] (dead before k_qkm writes sp)

__device__ __forceinline__ void store_out(__hip_bfloat16* p, float v) { *p = __float2bfloat16(v); }
__device__ __forceinline__ void store_out(float* p, float v) { *p = v; }

__device__ __forceinline__ short bf16bits(float v) {
  __hip_bfloat16 t = __float2bfloat16(v);
  return *reinterpret_cast<short*>(&t);
}
__device__ __forceinline__ float b2f(short u) {
  union { unsigned int i; float f; } x;
  x.i = ((unsigned int)(unsigned short)u) << 16;
  return x.f;
}

__device__ __forceinline__ void gload16(const void* g, void* l) {
  __builtin_amdgcn_global_load_lds((const __attribute__((address_space(1))) unsigned int*)g,
                                   (__attribute__((address_space(3))) unsigned int*)l, 16, 0, 0);
}

// fp32 [b][C][P] -> bf16 [b][P][C] transpose+convert (tiles 32c x 64p)
__global__ __launch_bounds__(256) void k_cvt_t(const float* __restrict__ in,
                                               __hip_bfloat16* __restrict__ outT) {
  const int p0 = blockIdx.x * 64;
  const int c0 = blockIdx.y * 32;
  const int b = blockIdx.z;
  __shared__ float t[32][65];
  const float* ib = in + (size_t)b * CC * HW;
  const int tid = threadIdx.x;
  {
    const int c = tid >> 3, pl = (tid & 7) * 8;
    const float* s = ib + (size_t)(c0 + c) * HW + p0 + pl;
#pragma unroll
    for (int j = 0; j < 8; ++j) t[c][pl + j] = s[j];
  }
  __syncthreads();
  {
    const int pl = tid >> 2, cl = (tid & 3) * 8;
    __hip_bfloat16* d = outT + (size_t)b * HW * CC + (size_t)(p0 + pl) * CC + c0 + cl;
#pragma unroll
    for (int j = 0; j < 8; ++j) d[j] = __float2bfloat16(t[cl + j][pl]);
  }
}

__global__ __launch_bounds__(256) void k_cvt_w(const float* __restrict__ in,
                                               __hip_bfloat16* __restrict__ out, int n) {
  const int i = blockIdx.x * 256 + threadIdx.x;
  if (i < n) out[i] = __float2bfloat16(in[i]);
}

// MFMA bf16 GEMM (qkv): out[b][o][p] = sum_c W[o][c] * xT[b][p][c]
template <int M, typename OutT>
__global__ __launch_bounds__(256) void k_gemm(const __hip_bfloat16* __restrict__ xT,
                                              const __hip_bfloat16* __restrict__ Wb,
                                              OutT* __restrict__ out) {
  const int pBase = blockIdx.x * 128;
  const int mBase = blockIdx.y * 192;
  const int b = blockIdx.z;
  __shared__ __hip_bfloat16 Al[6144];  // [mf(12)][kg(4)][row(16)][8]
  __shared__ __hip_bfloat16 Bl[4096];  // [nf(8)][kg(4)][col(16)][8]
  const int tid = threadIdx.x;
  const int wave = tid >> 6, lane = tid & 63;
  const int wm = wave >> 1, wn = wave & 1;
  const __hip_bfloat16* xb = xT + (size_t)b * HW * CC;
  char* Alc = (char*)Al;
  char* Blc = (char*)Bl;
  f32x4 acc[6][4] = {};

  for (int k0 = 0; k0 < CC; k0 += 32) {
#pragma unroll
    for (int is = 0; is < 3; ++is) {
      const int ci = is * 256 + tid;
      const int row = ci & 15, kg = (ci >> 4) & 3, mf = ci >> 6;
      gload16(Wb + (size_t)(mBase + mf * 16 + row) * CC + k0 + kg * 8,
              Alc + is * 4096 + wave * 1024);
    }
#pragma unroll
    for (int is = 0; is < 2; ++is) {
      const int ci = is * 256 + tid;
      const int col = ci & 15, kg = (ci >> 4) & 3, nf = ci >> 6;
      gload16(xb + (size_t)(pBase + nf * 16 + col) * CC + k0 + kg * 8,
              Blc + is * 4096 + wave * 1024);
    }
    __syncthreads();
    s16x8 a[6], bf[4];
#pragma unroll
    for (int i = 0; i < 6; ++i) a[i] = *(const s16x8*)(Alc + ((wm * 6 + i) << 10) + (lane << 4));
#pragma unroll
    for (int j = 0; j < 4; ++j) bf[j] = *(const s16x8*)(Blc + ((wn * 4 + j) << 10) + (lane << 4));
#pragma unroll
    for (int i = 0; i < 6; ++i)
#pragma unroll
      for (int j = 0; j < 4; ++j)
        acc[i][j] = __builtin_amdgcn_mfma_f32_16x16x32_bf16(a[i], bf[j], acc[i][j], 0, 0, 0);
    __syncthreads();
  }
  OutT* ob = out + (size_t)b * M * HW;
  const int r0 = (lane >> 4) * 4, cl = lane & 15;
#pragma unroll
  for (int i = 0; i < 6; ++i) {
    const int o = mBase + (wm * 6 + i) * 16 + r0;
#pragma unroll
    for (int j = 0; j < 4; ++j) {
      const int p = pBase + (wn * 4 + j) * 16 + cl;
      OutT* dst = ob + (size_t)o * HW + p;
#pragma unroll
      for (int r = 0; r < 4; ++r) store_out(dst + (size_t)r * HW, acc[i][j][r]);
    }
  }
}

// depthwise 3x3 pad 1; q/k natural + fused sumsq partials; v transposed to vt[f][j]
__global__ __launch_bounds__(256) void k_dwconv(const __hip_bfloat16* __restrict__ in,
                                                const float* __restrict__ wdw,
                                                __hip_bfloat16* __restrict__ out,
                                                __hip_bfloat16* __restrict__ vt,
                                                float* __restrict__ psum) {
  const int h0 = blockIdx.x * 32;
  const int c = blockIdx.y;
  const int b = blockIdx.z;
  __shared__ __hip_bfloat16 IN[34][152];  // data at cols 8..135; zeros 0..7,136..143; stride 304B
  __shared__ char TR[8192];
  const int tid = threadIdx.x;
  const __hip_bfloat16* src = in + ((size_t)b * C3 + c) * HW;
  if (tid < 68) {
    const int r = tid >> 1, col = (tid & 1) ? 136 : 0;
    *(s16x8*)(&IN[r][col]) = (s16x8){};
  }
#pragma unroll
  for (int it = 0; it < 3; ++it) {
    const int vi = it * 256 + tid;
    if (vi < 544) {
      const int r = vi >> 4, w8 = vi & 15;
      const int hg = h0 - 1 + r;
      s16x8 v = {};
      if (hg >= 0 && hg < HH) v = *(const s16x8*)(src + (size_t)hg * WW + w8 * 8);
      *(s16x8*)(&IN[r][8 + w8 * 8]) = v;
    }
  }
  const float* wp = wdw + c * 9;
  float wgt[9];
#pragma unroll
  for (int q = 0; q < 9; ++q) wgt[q] = wp[q];
  __syncthreads();

  const int hl = tid >> 3, w0 = (tid & 7) * 16;
  float res[16] = {};
#pragma unroll
  for (int dh = 0; dh < 3; ++dh) {
    const __hip_bfloat16* rp = &IN[hl + dh][0];
    const s16x8 v0 = *(const s16x8*)(rp + w0);
    const s16x8 v1 = *(const s16x8*)(rp + w0 + 8);
    const s16x8 v2 = *(const s16x8*)(rp + w0 + 16);
    const s16x8 v3 = *(const s16x8*)(rp + w0 + 24);
    float rv[18];
    rv[0] = b2f(v0[7]);
#pragma unroll
    for (int e = 0; e < 8; ++e) rv[1 + e] = b2f(v1[e]);
#pragma unroll
    for (int e = 0; e < 8; ++e) rv[9 + e] = b2f(v2[e]);
    rv[17] = b2f(v3[0]);
    const float wa = wgt[dh * 3], wb = wgt[dh * 3 + 1], wc = wgt[dh * 3 + 2];
#pragma unroll
    for (int ww = 0; ww < 16; ++ww)
      res[ww] += rv[ww] * wa + rv[ww + 1] * wb + rv[ww + 2] * wc;
  }
  if (c < 2 * CC) {  // q,k: natural layout + sumsq partial
    short pk[16];
#pragma unroll
    for (int ww = 0; ww < 16; ++ww) pk[ww] = bf16bits(res[ww]);
    __hip_bfloat16* dst = out + ((size_t)b * C3 + c) * HW + (size_t)(h0 + hl) * WW + w0;
    *(s16x8*)dst = *(const s16x8*)pk;
    *(s16x8*)(dst + 8) = *(const s16x8*)(pk + 8);
    float ss = 0.f;
#pragma unroll
    for (int ww = 0; ww < 16; ++ww) ss += res[ww] * res[ww];
#pragma unroll
    for (int off = 4; off > 0; off >>= 1) ss += __shfl_down(ss, off);
    if ((tid & 7) == 0) psum[((size_t)b * HH + h0 + hl) * 384 + c] = ss;
  } else {  // v: LDS transpose -> vt[(b*4+hd)][ch*128+w][h]
    const int rel = c - 2 * CC;
    const int hd = rel / CH, ch = rel - hd * CH;
#pragma unroll
    for (int ww = 0; ww < 16; ++ww) {
      const int w = w0 + ww;
      const int blk = ((w << 2) + (hl >> 3)) ^ ((w >> 3) & 3);
      *(short*)(TR + (blk << 4) + ((hl & 7) << 1)) = bf16bits(res[ww]);
    }
    __syncthreads();
    const int w = tid >> 1, hf = tid & 1;
    short ot[16];
#pragma unroll
    for (int j = 0; j < 2; ++j) {
      const int hh = hf * 16 + j * 8;
      const int blk = ((w << 2) + (hh >> 3)) ^ ((w >> 3) & 3);
      *(s16x8*)(ot + j * 8) = *(const s16x8*)(TR + (blk << 4));
    }
    __hip_bfloat16* vd = vt + ((size_t)(b * NH + hd) * FF + (size_t)ch * WW + w) * HH + h0 + hf * 16;
    *(s16x8*)vd = *(const s16x8*)ot;
    *(s16x8*)(vd + 8) = *(const s16x8*)(ot + 8);
  }
}

// tiny: reduce 48-ch partials -> reciprocal norms
__global__ __launch_bounds__(64) void k_norms2(const float* __restrict__ psum,
                                               float* __restrict__ rq, float* __restrict__ rk) {
  const int i = blockIdx.x;
  const int hd = blockIdx.y;
  const int b = blockIdx.z & 7;
  const int which = blockIdx.z >> 3;
  const int lane = threadIdx.x;
  float s = 0.f;
  if (lane < 48) s = psum[((size_t)b * HH + i) * 384 + which * CC + hd * CH + lane];
#pragma unroll
  for (int off = 32; off > 0; off >>= 1) s += __shfl_down(s, off);
  if (lane == 0) {
    const float n = sqrtf(s);
    float* dst = which ? rk : rq;
    dst[(b * NH + hd) * HH + i] = 1.f / fmaxf(n, 1e-12f);
  }
}

// MFMA QK^T partials: sp[ks][bh][i][j], K-split 8 x 768
__global__ __launch_bounds__(256) void k_qkm(const __hip_bfloat16* __restrict__ dw,
                                             float* __restrict__ sp) {
  const int ks = blockIdx.x;
  const int bh = blockIdx.y;
  const int b = bh >> 2, hd = bh & 3;
  const __hip_bfloat16* qb = dw + ((size_t)b * C3 + hd * CH) * HW;
  const __hip_bfloat16* kb = dw + ((size_t)b * C3 + CC + hd * CH) * HW;
  __shared__ __hip_bfloat16 Al[4096];
  __shared__ __hip_bfloat16 Bl[4096];
  char* Alc = (char*)Al;
  char* Blc = (char*)Bl;
  const int tid = threadIdx.x, wave = tid >> 6, lane = tid & 63;
  const int wm = wave >> 1, wn = wave & 1;
  f32x4 acc[4][4] = {};
  for (int chunk = 0; chunk < 24; ++chunk) {
    const int ch = ks * 6 + (chunk >> 2);
    const int w0 = (chunk & 3) * 32;
#pragma unroll
    for (int is = 0; is < 2; ++is) {
      const int ci = is * 256 + tid;
      const int row = ci & 15, kg = (ci >> 4) & 3, mf = ci >> 6;
      gload16(qb + (size_t)ch * HW + (mf * 16 + row) * WW + w0 + kg * 8,
              Alc + is * 4096 + wave * 1024);
    }
#pragma unroll
    for (int is = 0; is < 2; ++is) {
      const int ci = is * 256 + tid;
      const int col = ci & 15, kg = (ci >> 4) & 3, nf = ci >> 6;
      gload16(kb + (size_t)ch * HW + (nf * 16 + col) * WW + w0 + kg * 8,
              Blc + is * 4096 + wave * 1024);
    }
    __syncthreads();
    s16x8 a[4], bf[4];
#pragma unroll
    for (int i = 0; i < 4; ++i) a[i] = *(const s16x8*)(Alc + ((wm * 4 + i) << 10) + (lane << 4));
#pragma unroll
    for (int j = 0; j < 4; ++j) bf[j] = *(const s16x8*)(Blc + ((wn * 4 + j) << 10) + (lane << 4));
#pragma unroll
    for (int i = 0; i < 4; ++i)
#pragma unroll
      for (int j = 0; j < 4; ++j)
        acc[i][j] = __builtin_amdgcn_mfma_f32_16x16x32_bf16(a[i], bf[j], acc[i][j], 0, 0, 0);
    __syncthreads();
  }
  float* o = sp + (size_t)ks * SPM + (size_t)bh * HH * HH;
  const int r0 = (lane >> 4) * 4, cl = lane & 15;
#pragma unroll
  for (int i = 0; i < 4; ++i)
#pragma unroll
    for (int j = 0; j < 4; ++j) {
      const int ii = wm * 64 + i * 16 + r0;
      const int jj = wn * 64 + j * 16 + cl;
#pragma unroll
      for (int r = 0; r < 4; ++r) o[(ii + r) * HH + jj] = acc[i][j][r];
    }
}

// reduce partials, scale, softmax -> bf16 attn
__global__ __launch_bounds__(64) void k_softmax(const float* __restrict__ sp,
                                                const float* __restrict__ rq,
                                                const float* __restrict__ rk,
                                                const float* __restrict__ temp,
                                                __hip_bfloat16* __restrict__ atb) {
  const int i = blockIdx.x;
  const int bh = blockIdx.y;
  const int hd = bh & 3;
  const int lane = threadIdx.x;
  const size_t rowoff = ((size_t)bh * HH + i) * HH;
  float s0 = 0.f, s1 = 0.f;
#pragma unroll
  for (int ks = 0; ks < 8; ++ks) {
    s0 += sp[ks * SPM + rowoff + lane];
    s1 += sp[ks * SPM + rowoff + lane + 64];
  }
  const float scale = rq[bh * HH + i] * temp[hd];
  s0 *= scale * rk[bh * HH + lane];
  s1 *= scale * rk[bh * HH + lane + 64];
  float m = fmaxf(s0, s1);
#pragma unroll
  for (int off = 32; off > 0; off >>= 1) m = fmaxf(m, __shfl_xor(m, off));
  const float e0 = expf(s0 - m), e1 = expf(s1 - m);
  float ssum = e0 + e1;
#pragma unroll
  for (int off = 32; off > 0; off >>= 1) ssum += __shfl_xor(ssum, off);
  const float inv = 1.f / ssum;
  atb[rowoff + lane] = __float2bfloat16(e0 * inv);
  atb[rowoff + lane + 64] = __float2bfloat16(e1 * inv);
}

// MFMA PV: pvout[bh][i][f] = sum_j attn[bh][i][j] * vt[bh][f][j]
__global__ __launch_bounds__(256) void k_pvm(const __hip_bfloat16* __restrict__ atb,
                                             const __hip_bfloat16* __restrict__ vt,
                                             __hip_bfloat16* __restrict__ pvout) {
  const int fs = blockIdx.x;  // 0..23 (256 f each)
  const int bh = blockIdx.y;
  const __hip_bfloat16* ab = atb + (size_t)bh * HH * HH;
  const __hip_bfloat16* vb = vt + ((size_t)bh * FF + fs * 256) * HH;
  __shared__ __hip_bfloat16 Al[4096];
  __shared__ __hip_bfloat16 Bl[8192];
  char* Alc = (char*)Al;
  char* Blc = (char*)Bl;
  const int tid = threadIdx.x, wave = tid >> 6, lane = tid & 63;
  const int wm = wave >> 1, wn = wave & 1;
  f32x4 acc[4][8] = {};
  for (int kc = 0; kc < 4; ++kc) {
    const int kj0 = kc * 32;
#pragma unroll
    for (int is = 0; is < 2; ++is) {
      const int ci = is * 256 + tid;
      const int row = ci & 15, kg = (ci >> 4) & 3, mf = ci >> 6;
      gload16(ab + (size_t)(mf * 16 + row) * HH + kj0 + kg * 8,
              Alc + is * 4096 + wave * 1024);
    }
#pragma unroll
    for (int is = 0; is < 4; ++is) {
      const int ci = is * 256 + tid;
      const int col = ci & 15, kg = (ci >> 4) & 3, nf = ci >> 6;
      gload16(vb + (size_t)(nf * 16 + col) * HH + kj0 + kg * 8,
              Blc + is * 4096 + wave * 1024);
    }
    __syncthreads();
    s16x8 a[4], bf[8];
#pragma unroll
    for (int i = 0; i < 4; ++i) a[i] = *(const s16x8*)(Alc + ((wm * 4 + i) << 10) + (lane << 4));
#pragma unroll
    for (int j = 0; j < 8; ++j) bf[j] = *(const s16x8*)(Blc + ((wn * 8 + j) << 10) + (lane << 4));
#pragma unroll
    for (int i = 0; i < 4; ++i)
#pragma unroll
      for (int j = 0; j < 8; ++j)
        acc[i][j] = __builtin_amdgcn_mfma_f32_16x16x32_bf16(a[i], bf[j], acc[i][j], 0, 0, 0);
    __syncthreads();
  }
  __hip_bfloat16* ob = pvout + (size_t)bh * HH * FF;
  const int r0 = (lane >> 4) * 4, cl = lane & 15;
#pragma unroll
  for (int i = 0; i < 4; ++i)
#pragma unroll
    for (int j = 0; j < 8; ++j) {
      const int ii = wm * 64 + i * 16 + r0;
      const int f = fs * 256 + wn * 128 + j * 16 + cl;
#pragma unroll
      for (int r = 0; r < 4; ++r) ob[(size_t)(ii + r) * FF + f] = __float2bfloat16(acc[i][j][r]);
    }
}

// fused transpose+proj: out[b][o][i*128+w] = sum_{hd,ch} Wp[o][hd*48+ch]*pv[b*4+hd][i][ch*128+w]
__global__ __launch_bounds__(256) void k_proj(const __hip_bfloat16* __restrict__ pv,
                                              const __hip_bfloat16* __restrict__ Wp,
                                              float* __restrict__ out) {
  const int i = blockIdx.x;   // 0..127
  const int b = blockIdx.y;
  __shared__ __hip_bfloat16 Al[6144];      // 12KB [mf12][kg4][row16][8]
  __shared__ __hip_bfloat16 Braw[12288];   // 24KB swizzled [r96][w128]
  __shared__ __hip_bfloat16 Bfrag[12288];  // 24KB [nf8][kc3][lane64][8]
  char* Alc = (char*)Al;
  char* Brc = (char*)Braw;
  char* Bfc = (char*)Bfrag;
  const int tid = threadIdx.x, wave = tid >> 6, lane = tid & 63;
  const int wm = wave >> 1, wn = wave & 1;
  f32x4 acc[6][4] = {};
  for (int hf = 0; hf < 2; ++hf) {
    // phase 1: stage 96 c-rows x 128 w into swizzled Braw
#pragma unroll
    for (int it = 0; it < 6; ++it) {
      const int vi = it * 256 + tid;
      const int r = vi >> 4, w8 = vi & 15;
      const int hi = (r >= 48) ? 1 : 0;
      const int hd = hf * 2 + hi, ch = r - hi * 48;
      const s16x8 v = *(const s16x8*)(pv + ((size_t)(b * NH + hd) * HH + i) * FF + ch * 128 + w8 * 8);
      *(s16x8*)(Brc + r * 256 + ((w8 ^ (r & 15)) << 4)) = v;
    }
    __syncthreads();
    // phase 2: rebuild transposed fragment-linear Bfrag
#pragma unroll
    for (int it = 0; it < 6; ++it) {
      const int vi = it * 256 + tid;     // vi = (nf*12 + kg12)*16 + col
      const int col = vi & 15, kg12 = (vi >> 4) % 12, nf = vi / 192;
      const int w = nf * 16 + col;
      short tmp[8];
#pragma unroll
      for (int e = 0; e < 8; ++e) {
        const int r = kg12 * 8 + e;
        tmp[e] = *(const short*)(Brc + r * 256 + (((w >> 3) ^ (r & 15)) << 4) + (w & 7) * 2);
      }
      const int kc = kg12 >> 2, kg = kg12 & 3;
      *(s16x8*)(Bfc + (((nf * 3 + kc) * 64 + kg * 16 + col) << 4)) = *(const s16x8*)tmp;
    }
    for (int kc = 0; kc < 3; ++kc) {
      const int c0 = hf * 96 + kc * 32;
#pragma unroll
      for (int is = 0; is < 3; ++is) {
        const int ci = is * 256 + tid;
        const int row = ci & 15, kg = (ci >> 4) & 3, mf = ci >> 6;
        gload16(Wp + (size_t)(mf * 16 + row) * CC + c0 + kg * 8,
                Alc + is * 4096 + wave * 1024);
      }
      __syncthreads();   // drains gload + orders phase2 writes before frag reads
      s16x8 a[6], bf[4];
#pragma unroll
      for (int mi = 0; mi < 6; ++mi)
        a[mi] = *(const s16x8*)(Alc + ((wm * 6 + mi) << 10) + (lane << 4));
#pragma unroll
      for (int j = 0; j < 4; ++j)
        bf[j] = *(const s16x8*)(Bfc + ((((wn * 4 + j) * 3 + kc) * 64 + lane) << 4));
#pragma unroll
      for (int mi = 0; mi < 6; ++mi)
#pragma unroll
        for (int j = 0; j < 4; ++j)
          acc[mi][j] = __builtin_amdgcn_mfma_f32_16x16x32_bf16(a[mi], bf[j], acc[mi][j], 0, 0, 0);
      __syncthreads();   // before Al/Braw/Bfrag overwrite
    }
  }
  const int r0 = (lane >> 4) * 4, cl = lane & 15;
#pragma unroll
  for (int mi = 0; mi < 6; ++mi) {
    const int o = (wm * 6 + mi) * 16 + r0;
#pragma unroll
    for (int j = 0; j < 4; ++j) {
      const int w = (wn * 4 + j) * 16 + cl;
      float* dst = out + ((size_t)b * CC + o) * HW + i * 128 + w;
#pragma unroll
      for (int r = 0; r < 4; ++r) dst[(size_t)r * HW] = acc[mi][j][r];
    }
  }
}

extern "C" void kernel_launch(void* const* d_in, const int* in_sizes, int n_in,
                              void* d_out, int out_size, void* d_ws, size_t ws_size,
                              hipStream_t stream) {
  const float* x     = (const float*)d_in[0];
  const float* wqkv  = (const float*)d_in[1];
  const float* wdw   = (const float*)d_in[2];
  const float* wproj = (const float*)d_in[3];
  const float* temp  = (const float*)d_in[4];

  char* ws = (char*)d_ws;
  __hip_bfloat16* xTb    = (__hip_bfloat16*)(ws + OFF_XT);
  __hip_bfloat16* vt     = (__hip_bfloat16*)(ws + OFF_XT);   // xT dead after k_gemm
  __hip_bfloat16* Wq     = (__hip_bfloat16*)(ws + OFF_WQ);
  __hip_bfloat16* Wp     = (__hip_bfloat16*)(ws + OFF_WP);
  __hip_bfloat16* qkvraw = (__hip_bfloat16*)(ws + OFF_RAW);
  __hip_bfloat16* pvout  = (__hip_bfloat16*)(ws + OFF_RAW);  // qkvraw dead after dwconv
  __hip_bfloat16* qkvdw  = (__hip_bfloat16*)(ws + OFF_DW);
  float* sp    = (float*)(ws + OFF_SP);
  float* psum  = (float*)(ws + OFF_PS);                      // aliases sp; dead before k_qkm
  __hip_bfloat16* atb = (__hip_bfloat16*)(ws + OFF_ATB);
  float* rq    = (float*)(ws + OFF_RQ);
  float* rk    = (float*)(ws + OFF_RK);

  k_cvt_w<<<dim3((C3 * CC + 255) / 256), 256, 0, stream>>>(wqkv, Wq, C3 * CC);
  k_cvt_w<<<dim3((CC * CC + 255) / 256), 256, 0, stream>>>(wproj, Wp, CC * CC);
  k_cvt_t<<<dim3(HW / 64, CC / 32, BB), 256, 0, stream>>>(x, xTb);
  k_gemm<C3, __hip_bfloat16><<<dim3(HW / 128, 3, BB), 256, 0, stream>>>(xTb, Wq, qkvraw);
  k_dwconv<<<dim3(HH / 32, C3, BB), 256, 0, stream>>>(qkvraw, wdw, qkvdw, vt, psum);
  k_norms2<<<dim3(HH, NH, 2 * BB), 64, 0, stream>>>(psum, rq, rk);
  k_qkm<<<dim3(8, 32), 256, 0, stream>>>(qkvdw, sp);
  k_softmax<<<dim3(HH, 32), 64, 0, stream>>>(sp, rq, rk, temp, atb);
  k_pvm<<<dim3(24, 32), 256, 0, stream>>>(atb, vt, pvout);
  k_proj<<<dim3(HH, BB), 256, 0, stream>>>(pvout, Wp, (float*)d_out);
}